// Round 19
// baseline (289.714 us; speedup 1.0000x reference)
//
#include <hip/hip_runtime.h>

#define LL 4096
#define HH 1024
#define PP 512
#define RR 16
#define CH 128   // scan chunks
#define CL 32    // steps per chunk

typedef _Float16 f16x8 __attribute__((ext_vector_type(8)));
typedef float f32x4 __attribute__((ext_vector_type(4)));
typedef unsigned short u16;
typedef unsigned int u32;

#define MF16(a, b, c) __builtin_amdgcn_mfma_f32_16x16x32_f16(a, b, c, 0, 0, 0)

__device__ __forceinline__ u16 h16(float x) {
  _Float16 h = (_Float16)x;
  return __builtin_bit_cast(u16, h);
}
__device__ __forceinline__ float f16f(u16 v) {
  return (float)__builtin_bit_cast(_Float16, v);
}

// ---------------------------------------------------------------- precompute (tiny)
__global__ void precompute_kernel(const float* __restrict__ Lre, const float* __restrict__ Lim,
                                  const float* __restrict__ lst,
                                  const float* __restrict__ Ere, const float* __restrict__ Eim,
                                  const float* __restrict__ Fre, const float* __restrict__ Fim,
                                  float* __restrict__ Lbr, float* __restrict__ Lbi,
                                  float* __restrict__ cfr, float* __restrict__ cfi,
                                  float* __restrict__ EFr, float* __restrict__ EFi)
{
  int p = blockIdx.x * blockDim.x + threadIdx.x;
  if (p >= PP) return;
  float lre = fminf(Lre[p], -1e-4f);   // clip_eigs
  float lim = Lim[p];
  float st  = expf(lst[p]);
  float er  = expf(lre * st);
  float s, c;
  sincosf(lim * st, &s, &c);
  float lbr = er * c, lbi = er * s;    // Lambda_bar
  Lbr[p] = lbr; Lbi[p] = lbi;
  float den = lre * lre + lim * lim;
  float nr  = lbr - 1.0f;
  cfr[p] = (nr * lre + lbi * lim) / den;
  cfi[p] = (lbi * lre - nr * lim) / den;
  for (int r = 0; r < RR; ++r) {
    float e_r = Ere[p * RR + r], e_i = Eim[p * RR + r];
    float f_r = Fre[r * PP + p], f_i = Fim[r * PP + p];
    EFr[r * PP + p] = e_r * f_r - e_i * f_i;
    EFi[r * PP + p] = e_r * f_i + e_i * f_r;
  }
}

// ---------------------------------------------------------------- fused prep: bbar | prep_c | ext
__global__ __launch_bounds__(256) void prep2_kernel(
    const float* __restrict__ Bre, const float* __restrict__ Bim,
    const float* __restrict__ cfr, const float* __restrict__ cfi,
    const float* __restrict__ Cre, const float* __restrict__ Cim,
    const float* __restrict__ Dt, const float* __restrict__ EFr,
    const float* __restrict__ EFi,
    u16* __restrict__ B1, u32* __restrict__ B2, u32* __restrict__ LE)
{
  int g = blockIdx.x, t = threadIdx.x;
  if (g < 512) {
    int base = (g * 256 + t) * 4;
    int p = base >> 10, col = base & 1023;
    float cr = cfr[p], ci = cfi[p];
    float4 br = *(const float4*)&Bre[base];
    float4 bi = *(const float4*)&Bim[base];
    ushort4 rp, ip;
    rp.x = h16(cr*br.x - ci*bi.x); ip.x = h16(cr*bi.x + ci*br.x);
    rp.y = h16(cr*br.y - ci*bi.y); ip.y = h16(cr*bi.y + ci*br.y);
    rp.z = h16(cr*br.z - ci*bi.z); ip.z = h16(cr*bi.z + ci*br.z);
    rp.w = h16(cr*br.w - ci*bi.w); ip.w = h16(cr*bi.w + ci*br.w);
    *(ushort4*)&B1[(size_t)(2 * p) * 1024 + col] = rp;
    *(ushort4*)&B1[(size_t)(2 * p + 1) * 1024 + col] = ip;
  } else if (g < 1536) {
    int base = ((g - 512) * 256 + t) * 4;
    float4 a = *(const float4*)&Cre[base];
    float4 b = *(const float4*)&Cim[base];
    uint4 o;
    o.x = (u32)h16(a.x) | ((u32)h16(-b.x) << 16);
    o.y = (u32)h16(a.y) | ((u32)h16(-b.y) << 16);
    o.z = (u32)h16(a.z) | ((u32)h16(-b.z) << 16);
    o.w = (u32)h16(a.w) | ((u32)h16(-b.w) << 16);
    *(uint4*)&B2[base] = o;
  } else {
    int gid = (g - 1536) * 256 + t;
    int l  = gid >> 7;
    int pq = (gid & 127) << 2;
    float4 ar = {0.f, 0.f, 0.f, 0.f};
    float4 ai = {0.f, 0.f, 0.f, 0.f};
#pragma unroll
    for (int r = 0; r < RR; ++r) {
      float d = Dt[l * RR + r];
      float4 er = *(const float4*)&EFr[r * PP + pq];
      float4 ei = *(const float4*)&EFi[r * PP + pq];
      ar.x = fmaf(d, er.x, ar.x); ar.y = fmaf(d, er.y, ar.y);
      ar.z = fmaf(d, er.z, ar.z); ar.w = fmaf(d, er.w, ar.w);
      ai.x = fmaf(d, ei.x, ai.x); ai.y = fmaf(d, ei.y, ai.y);
      ai.z = fmaf(d, ei.z, ai.z); ai.w = fmaf(d, ei.w, ai.w);
    }
    uint4 o;
    o.x = (u32)h16(ar.x) | ((u32)h16(ai.x) << 16);
    o.y = (u32)h16(ar.y) | ((u32)h16(ai.y) << 16);
    o.z = (u32)h16(ar.z) | ((u32)h16(ai.z) << 16);
    o.w = (u32)h16(ar.w) | ((u32)h16(ai.w) << 16);
    *(uint4*)&LE[(size_t)l * PP + pq] = o;
  }
}

// ---------------------------------------------------------------- unified GEMM (8-wave 128x128, BK=64)
// (R16/R17 proven structure)
template<int EPI, bool ACVT>
__global__ __launch_bounds__(512) void gemm_k8(
    const void* __restrict__ Asrc, const u16* __restrict__ Bsrc, int Kp,
    void* __restrict__ outv, const float* __restrict__ Dv,
    const float* __restrict__ Uep)
{
  __shared__ __align__(16) uint4 lds[2 * 32 * 64];   // 64 KB
  int NT = Kp / 64;
  int bid = blockIdx.x;
  int n0 = (bid & 7) * 128;
  int m0 = (bid >> 3) * 128;
  int t = threadIdx.x, lane = t & 63, w = t >> 6;    // 8 waves
  int wr = w >> 2, wc = w & 3;                       // 2 x 4
  int rl = lane & 15, kg = lane >> 4;
  int srow = t >> 2, cch = t & 3;                    // staging row 0..127, quarter

  const float* Af = (const float*)Asrc;
  const u16*   Ah = (const u16*)Asrc;

  f32x4 acc[4][2];
#pragma unroll
  for (int m = 0; m < 4; ++m)
#pragma unroll
    for (int n = 0; n < 2; ++n) acc[m][n] = (f32x4){0.f, 0.f, 0.f, 0.f};

  struct Frags { uint4 a[2]; uint4 b[2]; };
  auto LOAD = [&](int kt) -> Frags {
    Frags f;
    if constexpr (ACVT) {
      const float* p = Af + (size_t)(m0 + srow) * Kp + kt * 64 + cch * 16;
#pragma unroll
      for (int j = 0; j < 2; ++j) {
        float4 a = *(const float4*)(p + j * 8), b = *(const float4*)(p + j * 8 + 4);
        f16x8 r;
        r[0] = (_Float16)a.x; r[1] = (_Float16)a.y; r[2] = (_Float16)a.z; r[3] = (_Float16)a.w;
        r[4] = (_Float16)b.x; r[5] = (_Float16)b.y; r[6] = (_Float16)b.z; r[7] = (_Float16)b.w;
        f.a[j] = __builtin_bit_cast(uint4, r);
      }
    } else {
      const u16* p = Ah + (size_t)(m0 + srow) * Kp + kt * 64 + cch * 16;
      f.a[0] = *(const uint4*)p;
      f.a[1] = *(const uint4*)(p + 8);
    }
    const u16* q = Bsrc + (size_t)(n0 + srow) * Kp + kt * 64 + cch * 16;
    f.b[0] = *(const uint4*)q;
    f.b[1] = *(const uint4*)(q + 8);
    return f;
  };
  auto WRITE = [&](int buf, const Frags& f) {
#pragma unroll
    for (int j = 0; j < 2; ++j) {
      int kq = cch * 2 + j;                            // 0..7
      int c = kq & 3;
      int slot = c * 16 + ((srow & 15) ^ (c * 2));
      int seg = (srow >> 4) * 2 + (kq >> 2);           // 0..15
      lds[buf * 2048 + seg * 64 + slot] = f.a[j];
      lds[buf * 2048 + (16 + seg) * 64 + slot] = f.b[j];
    }
  };

  Frags nxt, far;
  WRITE(0, LOAD(0));
  nxt = LOAD(1);
  __syncthreads();

  for (int kt = 0; kt < NT; ++kt) {
    int c = kt & 1;
    if (kt + 2 < NT) far = LOAD(kt + 2);
    int rslot = kg * 16 + (rl ^ (kg * 2));
    f16x8 af[4][2], bf[2][2];
#pragma unroll
    for (int m = 0; m < 4; ++m)
#pragma unroll
      for (int ks = 0; ks < 2; ++ks)
        af[m][ks] = __builtin_bit_cast(f16x8,
            lds[c * 2048 + ((wr * 4 + m) * 2 + ks) * 64 + rslot]);
#pragma unroll
    for (int n = 0; n < 2; ++n)
#pragma unroll
      for (int ks = 0; ks < 2; ++ks)
        bf[n][ks] = __builtin_bit_cast(f16x8,
            lds[c * 2048 + (16 + (wc * 2 + n) * 2 + ks) * 64 + rslot]);
#pragma unroll
    for (int ks = 0; ks < 2; ++ks)
#pragma unroll
      for (int m = 0; m < 4; ++m)
#pragma unroll
        for (int n = 0; n < 2; ++n)
          acc[m][n] = MF16(af[m][ks], bf[n][ks], acc[m][n]);
    if (kt + 1 < NT) WRITE(c ^ 1, nxt);
    nxt = far;
    __syncthreads();
  }

  // epilogue (registers only)
  if constexpr (EPI == 1) {
    float* Y = (float*)outv;
#pragma unroll
    for (int n = 0; n < 2; ++n) {
      int col = n0 + wc * 32 + n * 16 + rl;
      float dv = Dv[col];
#pragma unroll
      for (int m = 0; m < 4; ++m)
#pragma unroll
        for (int j = 0; j < 4; ++j) {
          int row = m0 + wr * 64 + m * 16 + kg * 4 + j;
          size_t idx = (size_t)row * 1024 + col;
          Y[idx] = 2.f * acc[m][n][j] + dv * Uep[idx];
        }
    }
  } else {
    // pack (re,im) of p = col/2 via lane-pair shfl (R15-verified)
    u32* P2 = (u32*)outv;
#pragma unroll
    for (int n = 0; n < 2; ++n) {
      int col = n0 + wc * 32 + n * 16 + rl;
#pragma unroll
      for (int m = 0; m < 4; ++m)
#pragma unroll
        for (int j = 0; j < 4; ++j) {
          int row = m0 + wr * 64 + m * 16 + kg * 4 + j;
          u32 hx = (u32)h16(acc[m][n][j]);
          u32 px = (u32)__shfl_xor((int)hx, 1);
          if ((rl & 1) == 0)
            P2[(size_t)row * 512 + (col >> 1)] = hx | (px << 16);
        }
    }
  }
}

// ---------------------------------------------------------------- scan phase 1 + fused carry
// 512 blocks x 256 thr. Each thread: chunk aggregate. Last finishing block
// (atomic counter) performs the serial carry for all 1024 sequences.
__global__ __launch_bounds__(256) void scan_agg_kernel(
    const float* __restrict__ Lbr, const float* __restrict__ Lbi,
    const u32* __restrict__ LE, const u32* __restrict__ P2,
    float* __restrict__ aggAr, float* __restrict__ aggAi,
    float* __restrict__ aggBr, float* __restrict__ aggBi,
    float* __restrict__ carR, float* __restrict__ carI,
    u32* __restrict__ counter)
{
  int tid = blockIdx.x * 256 + threadIdx.x;
  int p   = tid & (PP - 1);
  int c   = (tid >> 9) & (CH - 1);
  int dir = tid >> 16;
  float lbr = Lbr[p], lbi = Lbi[p];
  float Ar = 1.f, Ai = 0.f, br = 0.f, bi = 0.f;
  int base = c * CL;
#pragma unroll
  for (int g = 0; g < CL / 8; ++g) {
    float ar8[8], ai8[8], br8[8], bi8[8];
#pragma unroll
    for (int u = 0; u < 8; ++u) {
      int l = base + g * 8 + u;
      int phys = dir ? (LL - 1 - l) : l;
      u32 v = LE[(size_t)phys * PP + p];
      u32 bv = P2[(size_t)phys * PP + p];
      ar8[u] = lbr + f16f((u16)(v & 0xffff));
      ai8[u] = lbi + f16f((u16)(v >> 16));
      br8[u] = f16f((u16)(bv & 0xffff));
      bi8[u] = f16f((u16)(bv >> 16));
    }
#pragma unroll
    for (int u = 0; u < 8; ++u) {
      float nAr = ar8[u] * Ar - ai8[u] * Ai;
      float nAi = ar8[u] * Ai + ai8[u] * Ar;
      float nbr = fmaf(ar8[u], br, fmaf(-ai8[u], bi, br8[u]));
      float nbi = fmaf(ar8[u], bi, fmaf( ai8[u], br, bi8[u]));
      Ar = nAr; Ai = nAi; br = nbr; bi = nbi;
    }
  }
  aggAr[tid] = Ar; aggAi[tid] = Ai; aggBr[tid] = br; aggBi[tid] = bi;

  // last-block-done: the block that sees prev==511 runs the carry
  __threadfence();
  __syncthreads();
  __shared__ int lastBlk;
  if (threadIdx.x == 0)
    lastBlk = (atomicAdd(counter, 1u) == 511u) ? 1 : 0;
  __syncthreads();
  if (lastBlk) {
    // 256 threads handle 1024 sequences (4 each): seq = threadIdx.x + 256*q
#pragma unroll
    for (int q = 0; q < 4; ++q) {
      int s = threadIdx.x + 256 * q;         // dir*512 + p
      int p2   = s & (PP - 1);
      int dir2 = s >> 9;
      float xr = 0.f, xi = 0.f;
      for (int cc = 0; cc < CH; ++cc) {
        int idx = (dir2 * CH + cc) * PP + p2;
        carR[idx] = xr; carI[idx] = xi;
        float ar = aggAr[idx], ai = aggAi[idx];
        float b_r = aggBr[idx], b_i = aggBi[idx];
        float nr = fmaf(ar, xr, fmaf(-ai, xi, b_r));
        float ni = fmaf(ar, xi, fmaf( ai, xr, b_i));
        xr = nr; xi = ni;
      }
    }
  }
}

// ---------------------------------------------------------------- scan phase 3
__global__ __launch_bounds__(256) void scan_apply_kernel(
    const float* __restrict__ Lbr, const float* __restrict__ Lbi,
    const u32* __restrict__ LE, const u32* __restrict__ P2,
    const float* __restrict__ carR, const float* __restrict__ carI,
    u32* __restrict__ A2)
{
  int tid = blockIdx.x * 256 + threadIdx.x;
  int p   = tid & (PP - 1);
  int c   = (tid >> 9) & (CH - 1);
  int dir = tid >> 16;
  float lbr = Lbr[p], lbi = Lbi[p];
  float xr = carR[tid], xi = carI[tid];
  int base = c * CL;
  int cofs = dir * PP + p;
#pragma unroll
  for (int g = 0; g < CL / 8; ++g) {
    float ar8[8], ai8[8], br8[8], bi8[8];
#pragma unroll
    for (int u = 0; u < 8; ++u) {
      int l = base + g * 8 + u;
      int phys = dir ? (LL - 1 - l) : l;
      u32 v = LE[(size_t)phys * PP + p];
      u32 bv = P2[(size_t)phys * PP + p];
      ar8[u] = lbr + f16f((u16)(v & 0xffff));
      ai8[u] = lbi + f16f((u16)(v >> 16));
      br8[u] = f16f((u16)(bv & 0xffff));
      bi8[u] = f16f((u16)(bv >> 16));
    }
#pragma unroll
    for (int u = 0; u < 8; ++u) {
      float nr = fmaf(ar8[u], xr, fmaf(-ai8[u], xi, br8[u]));
      float ni = fmaf(ar8[u], xi, fmaf( ai8[u], xr, bi8[u]));
      xr = nr; xi = ni;
      int l = base + g * 8 + u;
      int phys = dir ? (LL - 1 - l) : l;
      A2[(size_t)phys * 1024 + cofs] = (u32)h16(xr) | ((u32)h16(xi) << 16);
    }
  }
}

// ---------------------------------------------------------------- launch
extern "C" void kernel_launch(void* const* d_in, const int* in_sizes, int n_in,
                              void* d_out, int out_size, void* d_ws, size_t ws_size,
                              hipStream_t stream)
{
  const float* U   = (const float*)d_in[0];
  const float* Lre = (const float*)d_in[1];
  const float* Lim = (const float*)d_in[2];
  const float* Bre = (const float*)d_in[3];
  const float* Bim = (const float*)d_in[4];
  const float* Cre = (const float*)d_in[5];
  const float* Cim = (const float*)d_in[6];
  const float* Ere = (const float*)d_in[7];
  const float* Eim = (const float*)d_in[8];
  const float* Fre = (const float*)d_in[9];
  const float* Fim = (const float*)d_in[10];
  const float* Dv  = (const float*)d_in[11];
  const float* lst = (const float*)d_in[12];
  const float* Dt  = (const float*)d_in[13];
  float* Y = (float*)d_out;

  char* wsb = (char*)d_ws;
  size_t o = 0;
  auto alloc = [&](size_t bytes) -> char* {
    char* r = wsb + o; o += (bytes + 255) & ~(size_t)255; return r;
  };
  float* Lbr = (float*)alloc(PP * 4);
  float* Lbi = (float*)alloc(PP * 4);
  float* cfr = (float*)alloc(PP * 4);
  float* cfi = (float*)alloc(PP * 4);
  float* EFr = (float*)alloc((size_t)RR * PP * 4);
  float* EFi = (float*)alloc((size_t)RR * PP * 4);
  u16* B1 = (u16*)alloc((size_t)1024 * 1024 * 2);   // rows 2p=re,2p+1=im of B_bar
  u32* B2 = (u32*)alloc((size_t)1024 * 1024 * 4);   // C interleaved (cr,-ci)
  u32* LE = (u32*)alloc((size_t)LL * PP * 4);       // ext packed fp16 pairs
  u32* P2 = (u32*)alloc((size_t)LL * PP * 4);       // Bu packed fp16 pairs
  u32* A2 = (u32*)alloc((size_t)LL * 1024 * 4);     // xs interleaved fp16 pairs
  const int NAGG = 2 * CH * PP;                     // 131072
  float* aggAr = (float*)alloc((size_t)NAGG * 4);
  float* aggAi = (float*)alloc((size_t)NAGG * 4);
  float* aggBr = (float*)alloc((size_t)NAGG * 4);
  float* aggBi = (float*)alloc((size_t)NAGG * 4);
  float* carR  = (float*)alloc((size_t)NAGG * 4);
  float* carI  = (float*)alloc((size_t)NAGG * 4);
  u32* counter = (u32*)alloc(256);

  hipMemsetAsync(counter, 0, 4, stream);
  precompute_kernel<<<2, 256, 0, stream>>>(Lre, Lim, lst, Ere, Eim, Fre, Fim,
                                           Lbr, Lbi, cfr, cfi, EFr, EFi);
  prep2_kernel<<<3584, 256, 0, stream>>>(Bre, Bim, cfr, cfi, Cre, Cim,
                                         Dt, EFr, EFi, B1, B2, LE);
  gemm_k8<2, true><<<256, 512, 0, stream>>>(U, B1, 1024, P2, nullptr, nullptr);
  scan_agg_kernel<<<512, 256, 0, stream>>>(Lbr, Lbi, LE, P2,
                                           aggAr, aggAi, aggBr, aggBi,
                                           carR, carI, counter);
  scan_apply_kernel<<<512, 256, 0, stream>>>(Lbr, Lbi, LE, P2, carR, carI, A2);
  gemm_k8<1, false><<<256, 512, 0, stream>>>(A2, (const u16*)B2, 2048, Y, Dv, U);
}

// Round 21
// 105.826 us; speedup vs baseline: 2.7376x; 2.7376x over previous
//
#include <hip/hip_runtime.h>

#define LL 4096
#define HH 1024
#define PP 512
#define RR 16
#define CH 128   // scan chunks
#define CL 32    // steps per chunk

typedef _Float16 f16x8 __attribute__((ext_vector_type(8)));
typedef float f32x4 __attribute__((ext_vector_type(4)));
typedef unsigned short u16;
typedef unsigned int u32;

#define MF16(a, b, c) __builtin_amdgcn_mfma_f32_16x16x32_f16(a, b, c, 0, 0, 0)

__device__ __forceinline__ u16 h16(float x) {
  _Float16 h = (_Float16)x;
  return __builtin_bit_cast(u16, h);
}
__device__ __forceinline__ float f16f(u16 v) {
  return (float)__builtin_bit_cast(_Float16, v);
}

// ---------------------------------------------------------------- precompute (tiny)
__global__ void precompute_kernel(const float* __restrict__ Lre, const float* __restrict__ Lim,
                                  const float* __restrict__ lst,
                                  const float* __restrict__ Ere, const float* __restrict__ Eim,
                                  const float* __restrict__ Fre, const float* __restrict__ Fim,
                                  float* __restrict__ Lbr, float* __restrict__ Lbi,
                                  float* __restrict__ cfr, float* __restrict__ cfi,
                                  float* __restrict__ EFr, float* __restrict__ EFi)
{
  int p = blockIdx.x * blockDim.x + threadIdx.x;
  if (p >= PP) return;
  float lre = fminf(Lre[p], -1e-4f);   // clip_eigs
  float lim = Lim[p];
  float st  = expf(lst[p]);
  float er  = expf(lre * st);
  float s, c;
  sincosf(lim * st, &s, &c);
  float lbr = er * c, lbi = er * s;    // Lambda_bar
  Lbr[p] = lbr; Lbi[p] = lbi;
  float den = lre * lre + lim * lim;
  float nr  = lbr - 1.0f;
  cfr[p] = (nr * lre + lbi * lim) / den;
  cfi[p] = (lbi * lre - nr * lim) / den;
  for (int r = 0; r < RR; ++r) {
    float e_r = Ere[p * RR + r], e_i = Eim[p * RR + r];
    float f_r = Fre[r * PP + p], f_i = Fim[r * PP + p];
    EFr[r * PP + p] = e_r * f_r - e_i * f_i;
    EFi[r * PP + p] = e_r * f_i + e_i * f_r;
  }
}

// ---------------------------------------------------------------- fused prep: bbar | prep_c | ext (R16-proven)
__global__ __launch_bounds__(256) void prep2_kernel(
    const float* __restrict__ Bre, const float* __restrict__ Bim,
    const float* __restrict__ cfr, const float* __restrict__ cfi,
    const float* __restrict__ Cre, const float* __restrict__ Cim,
    const float* __restrict__ Dt, const float* __restrict__ EFr,
    const float* __restrict__ EFi,
    u16* __restrict__ B1, u32* __restrict__ B2, u32* __restrict__ LE)
{
  int g = blockIdx.x, t = threadIdx.x;
  if (g < 512) {
    int base = (g * 256 + t) * 4;
    int p = base >> 10, col = base & 1023;
    float cr = cfr[p], ci = cfi[p];
    float4 br = *(const float4*)&Bre[base];
    float4 bi = *(const float4*)&Bim[base];
    ushort4 rp, ip;
    rp.x = h16(cr*br.x - ci*bi.x); ip.x = h16(cr*bi.x + ci*br.x);
    rp.y = h16(cr*br.y - ci*bi.y); ip.y = h16(cr*bi.y + ci*br.y);
    rp.z = h16(cr*br.z - ci*bi.z); ip.z = h16(cr*bi.z + ci*br.z);
    rp.w = h16(cr*br.w - ci*bi.w); ip.w = h16(cr*bi.w + ci*br.w);
    *(ushort4*)&B1[(size_t)(2 * p) * 1024 + col] = rp;
    *(ushort4*)&B1[(size_t)(2 * p + 1) * 1024 + col] = ip;
  } else if (g < 1536) {
    int base = ((g - 512) * 256 + t) * 4;
    float4 a = *(const float4*)&Cre[base];
    float4 b = *(const float4*)&Cim[base];
    uint4 o;
    o.x = (u32)h16(a.x) | ((u32)h16(-b.x) << 16);
    o.y = (u32)h16(a.y) | ((u32)h16(-b.y) << 16);
    o.z = (u32)h16(a.z) | ((u32)h16(-b.z) << 16);
    o.w = (u32)h16(a.w) | ((u32)h16(-b.w) << 16);
    *(uint4*)&B2[base] = o;
  } else {
    int gid = (g - 1536) * 256 + t;
    int l  = gid >> 7;
    int pq = (gid & 127) << 2;
    float4 ar = {0.f, 0.f, 0.f, 0.f};
    float4 ai = {0.f, 0.f, 0.f, 0.f};
#pragma unroll
    for (int r = 0; r < RR; ++r) {
      float d = Dt[l * RR + r];
      float4 er = *(const float4*)&EFr[r * PP + pq];
      float4 ei = *(const float4*)&EFi[r * PP + pq];
      ar.x = fmaf(d, er.x, ar.x); ar.y = fmaf(d, er.y, ar.y);
      ar.z = fmaf(d, er.z, ar.z); ar.w = fmaf(d, er.w, ar.w);
      ai.x = fmaf(d, ei.x, ai.x); ai.y = fmaf(d, ei.y, ai.y);
      ai.z = fmaf(d, ei.z, ai.z); ai.w = fmaf(d, ei.w, ai.w);
    }
    uint4 o;
    o.x = (u32)h16(ar.x) | ((u32)h16(ai.x) << 16);
    o.y = (u32)h16(ar.y) | ((u32)h16(ai.y) << 16);
    o.z = (u32)h16(ar.z) | ((u32)h16(ai.z) << 16);
    o.w = (u32)h16(ar.w) | ((u32)h16(ai.w) << 16);
    *(uint4*)&LE[(size_t)l * PP + pq] = o;
  }
}

// ---------------------------------------------------------------- U fp32 -> fp16 (R10-13-proven standalone)
__global__ __launch_bounds__(256) void uconv_kernel(const float* __restrict__ U,
                                                    u16* __restrict__ Uh)
{
  int i = (blockIdx.x * 256 + threadIdx.x) * 8;
  float4 a = *(const float4*)&U[i];
  float4 b = *(const float4*)&U[i + 4];
  f16x8 r;
  r[0] = (_Float16)a.x; r[1] = (_Float16)a.y; r[2] = (_Float16)a.z; r[3] = (_Float16)a.w;
  r[4] = (_Float16)b.x; r[5] = (_Float16)b.y; r[6] = (_Float16)b.z; r[7] = (_Float16)b.w;
  *(uint4*)&Uh[i] = __builtin_bit_cast(uint4, r);
}

// ---------------------------------------------------------------- gemm1 (R14/R16-proven: 64x64, BK=64, 4 waves)
// out = A[M][Kp] @ B[1024][Kp]^T; EPI 2: pack fp16 pairs. ACVT: fp32 A.
template<int EPI, bool ACVT>
__global__ __launch_bounds__(256) void gemm_k(
    const void* __restrict__ Asrc, const u16* __restrict__ Bsrc, int Kp,
    void* __restrict__ outv, const float* __restrict__ Dv,
    const float* __restrict__ Uep)
{
  __shared__ __align__(16) uint4 lds[2 * 16 * 64];   // 32 KB
  int bid = blockIdx.x;
  int n0 = ((bid & 7) * 2 + ((bid >> 3) & 1)) * 64;  // 16 n-tiles = 1024 cols
  int m0 = (bid >> 4) * 64;
  int t = threadIdx.x, lane = t & 63, w = t >> 6;
  int wr = w >> 1, wc = w & 1;
  int rl = lane & 15, kg = lane >> 4;
  int crow = t >> 2, cch = t & 3;
  int NT = Kp / 64;

  const float* Af = (const float*)Asrc;
  const u16*   Ah = (const u16*)Asrc;

  f32x4 acc[2][2];
  acc[0][0] = acc[0][1] = acc[1][0] = acc[1][1] = (f32x4){0.f, 0.f, 0.f, 0.f};

  struct Frags { uint4 a[2]; uint4 b[2]; };
  auto LOAD = [&](int kt) -> Frags {
    Frags f;
    if constexpr (ACVT) {
      const float* p = Af + (size_t)(m0 + crow) * Kp + kt * 64 + cch * 16;
#pragma unroll
      for (int j = 0; j < 2; ++j) {
        float4 a = *(const float4*)(p + j * 8), b = *(const float4*)(p + j * 8 + 4);
        f16x8 r;
        r[0] = (_Float16)a.x; r[1] = (_Float16)a.y; r[2] = (_Float16)a.z; r[3] = (_Float16)a.w;
        r[4] = (_Float16)b.x; r[5] = (_Float16)b.y; r[6] = (_Float16)b.z; r[7] = (_Float16)b.w;
        f.a[j] = __builtin_bit_cast(uint4, r);
      }
    } else {
      const u16* p = Ah + (size_t)(m0 + crow) * Kp + kt * 64 + cch * 16;
      f.a[0] = *(const uint4*)p;
      f.a[1] = *(const uint4*)(p + 8);
    }
    const u16* q = Bsrc + (size_t)(n0 + crow) * Kp + kt * 64 + cch * 16;
    f.b[0] = *(const uint4*)q;
    f.b[1] = *(const uint4*)(q + 8);
    return f;
  };
  auto WRITE = [&](int buf, const Frags& f) {
#pragma unroll
    for (int j = 0; j < 2; ++j) {
      int kq = cch * 2 + j;
      int c = kq & 3;
      int slot = c * 16 + ((crow & 15) ^ (c * 2));
      int segA = (crow >> 4) * 2 + (kq >> 2);
      lds[buf * 1024 + segA * 64 + slot] = f.a[j];
      lds[buf * 1024 + (8 + segA) * 64 + slot] = f.b[j];
    }
  };

  Frags nxt, far;
  WRITE(0, LOAD(0));
  nxt = LOAD(1);
  __syncthreads();

  for (int kt = 0; kt < NT; ++kt) {
    int c = kt & 1;
    if (kt + 2 < NT) far = LOAD(kt + 2);
    int rslot = kg * 16 + (rl ^ (kg * 2));
    f16x8 af[2][2], bf[2][2];
#pragma unroll
    for (int m = 0; m < 2; ++m)
#pragma unroll
      for (int ks = 0; ks < 2; ++ks) {
        int segA = (wr * 2 + m) * 2 + ks;
        int segB = 8 + (wc * 2 + m) * 2 + ks;
        af[m][ks] = __builtin_bit_cast(f16x8, lds[c * 1024 + segA * 64 + rslot]);
        bf[m][ks] = __builtin_bit_cast(f16x8, lds[c * 1024 + segB * 64 + rslot]);
      }
#pragma unroll
    for (int ks = 0; ks < 2; ++ks)
#pragma unroll
      for (int m = 0; m < 2; ++m)
#pragma unroll
        for (int n = 0; n < 2; ++n)
          acc[m][n] = MF16(af[m][ks], bf[n][ks], acc[m][n]);
    if (kt + 1 < NT) WRITE(c ^ 1, nxt);
    nxt = far;
    __syncthreads();
  }

  // epilogue: stage in LDS (reuse), vector stores
  float* Stg = (float*)lds;   // [64][68]
#pragma unroll
  for (int m = 0; m < 2; ++m)
#pragma unroll
    for (int n = 0; n < 2; ++n)
#pragma unroll
      for (int j = 0; j < 4; ++j)
        Stg[(wr * 32 + m * 16 + kg * 4 + j) * 68 + wc * 32 + n * 16 + rl] = acc[m][n][j];
  __syncthreads();
  int col4 = (t & 15) * 4, prow = t >> 4;
#pragma unroll
  for (int i = 0; i < 4; ++i) {
    int r = prow + 16 * i;
    float4 v = *(const float4*)&Stg[r * 68 + col4];
    if constexpr (EPI == 2) {
      uint2 pk;
      pk.x = (u32)h16(v.x) | ((u32)h16(v.y) << 16);
      pk.y = (u32)h16(v.z) | ((u32)h16(v.w) << 16);
      u32* outp = (u32*)outv;
      *(uint2*)&outp[(size_t)(m0 + r) * 512 + (n0 + col4) / 2] = pk;
    } else {
      float* out = (float*)outv;
      size_t ob = (size_t)(m0 + r) * 1024 + n0 + col4;
      if constexpr (EPI == 1) {
        float4 u4 = *(const float4*)&Uep[ob];
        float4 dv = *(const float4*)&Dv[n0 + col4];
        v.x = 2.f * v.x + dv.x * u4.x; v.y = 2.f * v.y + dv.y * u4.y;
        v.z = 2.f * v.z + dv.z * u4.z; v.w = 2.f * v.w + dv.w * u4.w;
      }
      *(float4*)&out[ob] = v;
    }
  }
}

// ---------------------------------------------------------------- gemm2: 128x128, BK=64, 8 waves (R16-proven)
__global__ __launch_bounds__(512) void gemm2_k8(
    const u16* __restrict__ Asrc, const u16* __restrict__ Bsrc,
    float* __restrict__ Y, const float* __restrict__ Dv,
    const float* __restrict__ Uep)
{
  __shared__ __align__(16) uint4 lds[2 * 32 * 64];   // 64 KB
  const int Kp = 2048, NT = 32;
  int bid = blockIdx.x;
  int n0 = (bid & 7) * 128;
  int m0 = (bid >> 3) * 128;
  int t = threadIdx.x, lane = t & 63, w = t >> 6;    // 8 waves
  int wr = w >> 2, wc = w & 3;                       // 2 x 4
  int rl = lane & 15, kg = lane >> 4;
  int srow = t >> 2, cch = t & 3;                    // staging row 0..127, quarter

  f32x4 acc[4][2];
#pragma unroll
  for (int m = 0; m < 4; ++m)
#pragma unroll
    for (int n = 0; n < 2; ++n) acc[m][n] = (f32x4){0.f, 0.f, 0.f, 0.f};

  struct Frags { uint4 a[2]; uint4 b[2]; };
  auto LOAD = [&](int kt) -> Frags {
    Frags f;
    const u16* p = Asrc + (size_t)(m0 + srow) * Kp + kt * 64 + cch * 16;
    f.a[0] = *(const uint4*)p;
    f.a[1] = *(const uint4*)(p + 8);
    const u16* q = Bsrc + (size_t)(n0 + srow) * Kp + kt * 64 + cch * 16;
    f.b[0] = *(const uint4*)q;
    f.b[1] = *(const uint4*)(q + 8);
    return f;
  };
  auto WRITE = [&](int buf, const Frags& f) {
#pragma unroll
    for (int j = 0; j < 2; ++j) {
      int kq = cch * 2 + j;                            // 0..7
      int c = kq & 3;
      int slot = c * 16 + ((srow & 15) ^ (c * 2));
      int seg = (srow >> 4) * 2 + (kq >> 2);           // 0..15
      lds[buf * 2048 + seg * 64 + slot] = f.a[j];
      lds[buf * 2048 + (16 + seg) * 64 + slot] = f.b[j];
    }
  };

  Frags nxt, far;
  WRITE(0, LOAD(0));
  nxt = LOAD(1);
  __syncthreads();

  for (int kt = 0; kt < NT; ++kt) {
    int c = kt & 1;
    if (kt + 2 < NT) far = LOAD(kt + 2);
    int rslot = kg * 16 + (rl ^ (kg * 2));
    f16x8 af[4][2], bf[2][2];
#pragma unroll
    for (int m = 0; m < 4; ++m)
#pragma unroll
      for (int ks = 0; ks < 2; ++ks)
        af[m][ks] = __builtin_bit_cast(f16x8,
            lds[c * 2048 + ((wr * 4 + m) * 2 + ks) * 64 + rslot]);
#pragma unroll
    for (int n = 0; n < 2; ++n)
#pragma unroll
      for (int ks = 0; ks < 2; ++ks)
        bf[n][ks] = __builtin_bit_cast(f16x8,
            lds[c * 2048 + (16 + (wc * 2 + n) * 2 + ks) * 64 + rslot]);
#pragma unroll
    for (int ks = 0; ks < 2; ++ks)
#pragma unroll
      for (int m = 0; m < 4; ++m)
#pragma unroll
        for (int n = 0; n < 2; ++n)
          acc[m][n] = MF16(af[m][ks], bf[n][ks], acc[m][n]);
    if (kt + 1 < NT) WRITE(c ^ 1, nxt);
    nxt = far;
    __syncthreads();
  }

  // epilogue: direct stores
#pragma unroll
  for (int n = 0; n < 2; ++n) {
    int col = n0 + wc * 32 + n * 16 + rl;
    float dv = Dv[col];
#pragma unroll
    for (int m = 0; m < 4; ++m)
#pragma unroll
      for (int j = 0; j < 4; ++j) {
        int row = m0 + wr * 64 + m * 16 + kg * 4 + j;
        size_t idx = (size_t)row * 1024 + col;
        Y[idx] = 2.f * acc[m][n][j] + dv * Uep[idx];
      }
  }
}

// ---------------------------------------------------------------- scan phase 1
__global__ __launch_bounds__(256) void scan_agg_kernel(
    const float* __restrict__ Lbr, const float* __restrict__ Lbi,
    const u32* __restrict__ LE, const u32* __restrict__ P2,
    float* __restrict__ aggAr, float* __restrict__ aggAi,
    float* __restrict__ aggBr, float* __restrict__ aggBi)
{
  int tid = blockIdx.x * 256 + threadIdx.x;
  int p   = tid & (PP - 1);
  int c   = (tid >> 9) & (CH - 1);
  int dir = tid >> 16;
  float lbr = Lbr[p], lbi = Lbi[p];
  float Ar = 1.f, Ai = 0.f, br = 0.f, bi = 0.f;
  int base = c * CL;
#pragma unroll
  for (int g = 0; g < CL / 8; ++g) {
    float ar8[8], ai8[8], br8[8], bi8[8];
#pragma unroll
    for (int u = 0; u < 8; ++u) {
      int l = base + g * 8 + u;
      int phys = dir ? (LL - 1 - l) : l;
      u32 v = LE[(size_t)phys * PP + p];
      u32 bv = P2[(size_t)phys * PP + p];
      ar8[u] = lbr + f16f((u16)(v & 0xffff));
      ai8[u] = lbi + f16f((u16)(v >> 16));
      br8[u] = f16f((u16)(bv & 0xffff));
      bi8[u] = f16f((u16)(bv >> 16));
    }
#pragma unroll
    for (int u = 0; u < 8; ++u) {
      float nAr = ar8[u] * Ar - ai8[u] * Ai;
      float nAi = ar8[u] * Ai + ai8[u] * Ar;
      float nbr = fmaf(ar8[u], br, fmaf(-ai8[u], bi, br8[u]));
      float nbi = fmaf(ar8[u], bi, fmaf( ai8[u], br, bi8[u]));
      Ar = nAr; Ai = nAi; br = nbr; bi = nbi;
    }
  }
  aggAr[tid] = Ar; aggAi[tid] = Ai; aggBr[tid] = br; aggBi[tid] = bi;
}

// ---------------------------------------------------------------- scan phase 2 (4 blocks, 1024 threads)
__global__ __launch_bounds__(256) void scan_carry_kernel(
    const float* __restrict__ aggAr, const float* __restrict__ aggAi,
    const float* __restrict__ aggBr, const float* __restrict__ aggBi,
    float* __restrict__ carR, float* __restrict__ carI)
{
  int tid = blockIdx.x * 256 + threadIdx.x;
  int p   = tid & (PP - 1);
  int dir = tid >> 9;
  float xr = 0.f, xi = 0.f;
  for (int c = 0; c < CH; ++c) {
    int idx = (dir * CH + c) * PP + p;
    carR[idx] = xr; carI[idx] = xi;
    float ar = aggAr[idx], ai = aggAi[idx];
    float br = aggBr[idx], bi = aggBi[idx];
    float nr = fmaf(ar, xr, fmaf(-ai, xi, br));
    float ni = fmaf(ar, xi, fmaf( ai, xr, bi));
    xr = nr; xi = ni;
  }
}

// ---------------------------------------------------------------- scan phase 3
__global__ __launch_bounds__(256) void scan_apply_kernel(
    const float* __restrict__ Lbr, const float* __restrict__ Lbi,
    const u32* __restrict__ LE, const u32* __restrict__ P2,
    const float* __restrict__ carR, const float* __restrict__ carI,
    u32* __restrict__ A2)
{
  int tid = blockIdx.x * 256 + threadIdx.x;
  int p   = tid & (PP - 1);
  int c   = (tid >> 9) & (CH - 1);
  int dir = tid >> 16;
  float lbr = Lbr[p], lbi = Lbi[p];
  float xr = carR[tid], xi = carI[tid];
  int base = c * CL;
  int cofs = dir * PP + p;
#pragma unroll
  for (int g = 0; g < CL / 8; ++g) {
    float ar8[8], ai8[8], br8[8], bi8[8];
#pragma unroll
    for (int u = 0; u < 8; ++u) {
      int l = base + g * 8 + u;
      int phys = dir ? (LL - 1 - l) : l;
      u32 v = LE[(size_t)phys * PP + p];
      u32 bv = P2[(size_t)phys * PP + p];
      ar8[u] = lbr + f16f((u16)(v & 0xffff));
      ai8[u] = lbi + f16f((u16)(v >> 16));
      br8[u] = f16f((u16)(bv & 0xffff));
      bi8[u] = f16f((u16)(bv >> 16));
    }
#pragma unroll
    for (int u = 0; u < 8; ++u) {
      float nr = fmaf(ar8[u], xr, fmaf(-ai8[u], xi, br8[u]));
      float ni = fmaf(ar8[u], xi, fmaf( ai8[u], xr, bi8[u]));
      xr = nr; xi = ni;
      int l = base + g * 8 + u;
      int phys = dir ? (LL - 1 - l) : l;
      A2[(size_t)phys * 1024 + cofs] = (u32)h16(xr) | ((u32)h16(xi) << 16);
    }
  }
}

// ---------------------------------------------------------------- launch
extern "C" void kernel_launch(void* const* d_in, const int* in_sizes, int n_in,
                              void* d_out, int out_size, void* d_ws, size_t ws_size,
                              hipStream_t stream)
{
  const float* U   = (const float*)d_in[0];
  const float* Lre = (const float*)d_in[1];
  const float* Lim = (const float*)d_in[2];
  const float* Bre = (const float*)d_in[3];
  const float* Bim = (const float*)d_in[4];
  const float* Cre = (const float*)d_in[5];
  const float* Cim = (const float*)d_in[6];
  const float* Ere = (const float*)d_in[7];
  const float* Eim = (const float*)d_in[8];
  const float* Fre = (const float*)d_in[9];
  const float* Fim = (const float*)d_in[10];
  const float* Dv  = (const float*)d_in[11];
  const float* lst = (const float*)d_in[12];
  const float* Dt  = (const float*)d_in[13];
  float* Y = (float*)d_out;

  char* wsb = (char*)d_ws;
  size_t o = 0;
  auto alloc = [&](size_t bytes) -> char* {
    char* r = wsb + o; o += (bytes + 255) & ~(size_t)255; return r;
  };
  float* Lbr = (float*)alloc(PP * 4);
  float* Lbi = (float*)alloc(PP * 4);
  float* cfr = (float*)alloc(PP * 4);
  float* cfi = (float*)alloc(PP * 4);
  float* EFr = (float*)alloc((size_t)RR * PP * 4);
  float* EFi = (float*)alloc((size_t)RR * PP * 4);
  u16* B1 = (u16*)alloc((size_t)1024 * 1024 * 2);   // rows 2p=re,2p+1=im of B_bar
  u32* B2 = (u32*)alloc((size_t)1024 * 1024 * 4);   // C interleaved (cr,-ci)
  u32* LE = (u32*)alloc((size_t)LL * PP * 4);       // ext packed fp16 pairs
  u16* Uh = (u16*)alloc((size_t)LL * HH * 2);       // U fp16
  u32* P2 = (u32*)alloc((size_t)LL * PP * 4);       // Bu packed fp16 pairs
  u32* A2 = (u32*)alloc((size_t)LL * 1024 * 4);     // xs interleaved fp16 pairs
  const int NAGG = 2 * CH * PP;                     // 131072
  float* aggAr = (float*)alloc((size_t)NAGG * 4);
  float* aggAi = (float*)alloc((size_t)NAGG * 4);
  float* aggBr = (float*)alloc((size_t)NAGG * 4);
  float* aggBi = (float*)alloc((size_t)NAGG * 4);
  float* carR  = (float*)alloc((size_t)NAGG * 4);
  float* carI  = (float*)alloc((size_t)NAGG * 4);

  precompute_kernel<<<2, 256, 0, stream>>>(Lre, Lim, lst, Ere, Eim, Fre, Fim,
                                           Lbr, Lbi, cfr, cfi, EFr, EFi);
  prep2_kernel<<<3584, 256, 0, stream>>>(Bre, Bim, cfr, cfi, Cre, Cim,
                                         Dt, EFr, EFi, B1, B2, LE);
  uconv_kernel<<<LL * HH / 8 / 256, 256, 0, stream>>>(U, Uh);
  gemm_k<2, false><<<1024, 256, 0, stream>>>(Uh, B1, 1024, P2, nullptr, nullptr);
  scan_agg_kernel<<<2 * CH * PP / 256, 256, 0, stream>>>(Lbr, Lbi, LE, P2,
                                                         aggAr, aggAi, aggBr, aggBi);
  scan_carry_kernel<<<4, 256, 0, stream>>>(aggAr, aggAi, aggBr, aggBi, carR, carI);
  scan_apply_kernel<<<2 * CH * PP / 256, 256, 0, stream>>>(Lbr, Lbi, LE, P2, carR, carI, A2);
  gemm2_k8<<<256, 512, 0, stream>>>((const u16*)A2, (const u16*)B2, Y, Dv, U);
}